// Round 16
// baseline (94.330 us; speedup 1.0000x reference)
//
#include <hip/hip_runtime.h>

typedef __bf16  bf16x8 __attribute__((ext_vector_type(8)));
typedef float   f32x4  __attribute__((ext_vector_type(4)));
typedef short   short8 __attribute__((ext_vector_type(8)));

static __device__ __forceinline__ unsigned short f2bf(float f) {
  union { float f; unsigned int u; } v; v.f = f;
  unsigned int u = v.u;
  u += 0x7fffu + ((u >> 16) & 1u);   // round-to-nearest-even
  return (unsigned short)(u >> 16);
}

// e2m1 decode: code = sign<<3 | e<<1 | m ; values {0,.5,1,1.5,2,3,4,6} * sign
static __device__ __forceinline__ float fp4_decode(int qc) {
  int e = (qc >> 1) & 3;
  float m = (float)(qc & 1);
  float mag = (e == 0) ? (0.5f * m)
                       : ((2.0f + m) * 0.5f * (float)(1 << (e - 1)));
  return (qc & 8) ? -mag : mag;
}

// Fused prep (R4-proven): blocks [0, nblkW/256) dequant W; rest convert x.
__global__ __launch_bounds__(256) void w4a16_prep(
    const int* __restrict__ wq, const float* __restrict__ wsc,
    short* __restrict__ wout, int nblkW,
    const float* __restrict__ x, short* __restrict__ xb, int n8) {
  const int nbW = nblkW >> 8;
  if ((int)blockIdx.x < nbW) {
    int idx = blockIdx.x * 256 + threadIdx.x;
    if (idx >= nblkW) return;
    float s = wsc[idx];
    const int4* qp = (const int4*)wq + (size_t)idx * 4;
    int4 q0 = qp[0], q1 = qp[1], q2 = qp[2], q3 = qp[3];
    short8 r0, r1;
    r0[0] = (short)f2bf(fp4_decode(q0.x) * s);
    r0[1] = (short)f2bf(fp4_decode(q0.y) * s);
    r0[2] = (short)f2bf(fp4_decode(q0.z) * s);
    r0[3] = (short)f2bf(fp4_decode(q0.w) * s);
    r0[4] = (short)f2bf(fp4_decode(q1.x) * s);
    r0[5] = (short)f2bf(fp4_decode(q1.y) * s);
    r0[6] = (short)f2bf(fp4_decode(q1.z) * s);
    r0[7] = (short)f2bf(fp4_decode(q1.w) * s);
    r1[0] = (short)f2bf(fp4_decode(q2.x) * s);
    r1[1] = (short)f2bf(fp4_decode(q2.y) * s);
    r1[2] = (short)f2bf(fp4_decode(q2.z) * s);
    r1[3] = (short)f2bf(fp4_decode(q2.w) * s);
    r1[4] = (short)f2bf(fp4_decode(q3.x) * s);
    r1[5] = (short)f2bf(fp4_decode(q3.y) * s);
    r1[6] = (short)f2bf(fp4_decode(q3.z) * s);
    r1[7] = (short)f2bf(fp4_decode(q3.w) * s);
    short8* op = (short8*)wout + (size_t)idx * 2;
    op[0] = r0;
    op[1] = r1;
  } else {
    int idx = (blockIdx.x - nbW) * 256 + threadIdx.x;
    if (idx >= n8) return;
    const float4* xp = (const float4*)x + (size_t)idx * 2;
    float4 a = xp[0], b = xp[1];
    short8 r;
    r[0] = (short)f2bf(a.x); r[1] = (short)f2bf(a.y);
    r[2] = (short)f2bf(a.z); r[3] = (short)f2bf(a.w);
    r[4] = (short)f2bf(b.x); r[5] = (short)f2bf(b.y);
    r[6] = (short)f2bf(b.z); r[7] = (short)f2bf(b.w);
    ((short8*)xb)[idx] = r;
  }
}

// ---------------------------------------------------------------------------
// C[M,N] = A[M,K] * B[N,K]^T, bf16 in, fp32 out.
// R4's HW-PROVEN skeleton (BM=128 x BN=256, BK=64, 8 waves 2x4, NBUF=3,
// stage-2-ahead, ONE {sched_barrier + vmcnt(6) + s_barrier} per K-tile),
// refactored for zero per-tile address VALU (R15 diagnosis: VALUBusy 20% =
// ~520 cyc/tile of addr recompute competing with MFMA issue):
//  - all 16 ds_read addresses hoisted to loop-invariant pointers,
//  - main loop unrolled x3 over the NBUF rotation -> buffer bases are
//    compile-time immediates, no cur/nxt rotation code,
//  - T1 bijective XCD swizzle (nwg=256 % 8 == 0): each XCD owns 2 A-panel
//    rows -> A-panel stays L2-hot.
// Swizzle (T2): 16B-chunk c XOR (row&7) on SOURCE and READ.
// ---------------------------------------------------------------------------
#define BM 128
#define BN 256
#define BK 64
#define NBUF 3
#define ASZ (BM * BK)          // 8192 shorts = 16KB
#define BSZ (BN * BK)          // 16384 shorts = 32KB
#define NT  64                 // K / BK

__global__ __launch_bounds__(512, 2) void w4a16_gemm_u3(
    const short* __restrict__ A, const short* __restrict__ B,
    float* __restrict__ C, int M, int N, int K) {
  __shared__ __attribute__((aligned(16))) short As[NBUF * ASZ];  // 48KB
  __shared__ __attribute__((aligned(16))) short Bs[NBUF * BSZ];  // 96KB

  const int tid  = threadIdx.x;
  const int lane = tid & 63;
  const int wid  = tid >> 6;      // 0..7
  const int wr   = wid >> 2;      // 0..1  (M)
  const int wc   = wid & 3;       // 0..3  (N)

  // T1: bijective XCD swizzle (nwg % 8 == 0 here: 16x16=256)
  const int nbx  = gridDim.x;
  const int nwg  = nbx * gridDim.y;
  const int orig = blockIdx.y * nbx + blockIdx.x;
  const int q8   = nwg >> 3;
  const int swz  = (orig & 7) * q8 + (orig >> 3);
  const int bn   = (swz % nbx) * BN;
  const int bm   = (swz / nbx) * BM;

  f32x4 acc[4][4] = {};           // [m-frag][n-frag]

  const int fr    = lane & 15;
  const int klane = lane >> 4;
  const int xv    = fr & 7;       // read-side swizzle XOR

  const size_t rowbytes = (size_t)K * 2;

  // ---- loop-invariant staging addresses (per-thread): only kt varies.
  size_t aoff[2];  int aldso[2];
#pragma unroll
  for (int r = 0; r < 2; ++r) {
    int u = r * 512 + tid;               // 0..1023
    int row = u >> 3, c = u & 7;
    int csrc = c ^ (row & 7);
    aoff[r]  = (size_t)(bm + row) * rowbytes + (size_t)csrc * 16;
    aldso[r] = u * 16;
  }
  size_t boff[4];  int bldso[4];
#pragma unroll
  for (int r = 0; r < 4; ++r) {
    int u = r * 512 + tid;               // 0..2047
    int row = u >> 3, c = u & 7;
    int csrc = c ^ (row & 7);
    boff[r]  = (size_t)(bn + row) * rowbytes + (size_t)csrc * 16;
    bldso[r] = u * 16;
  }

  const char* Ag = (const char*)A;
  const char* Bg = (const char*)B;

#define STAGE_A(bufn, koff2, r)                                                 \
  __builtin_amdgcn_global_load_lds(                                             \
      (const __attribute__((address_space(1))) unsigned int*)(Ag + aoff[r] + (koff2)), \
      (__attribute__((address_space(3))) unsigned int*)((char*)As + (bufn) * 16384 + aldso[r]), \
      16, 0, 0)
#define STAGE_B(bufn, koff2, r)                                                 \
  __builtin_amdgcn_global_load_lds(                                             \
      (const __attribute__((address_space(1))) unsigned int*)(Bg + boff[r] + (koff2)), \
      (__attribute__((address_space(3))) unsigned int*)((char*)Bs + (bufn) * 32768 + bldso[r]), \
      16, 0, 0)

  // ---- loop-invariant fragment-read pointers (buf 0 base; buf offset is a
  //      compile-time immediate in the unrolled loop)
  const char* ard[4][2];
  const char* brd[4][2];
#pragma unroll
  for (int mi = 0; mi < 4; ++mi)
#pragma unroll
    for (int kk = 0; kk < 2; ++kk) {
      int row = wr * 64 + mi * 16 + fr;
      int c = kk * 4 + klane;
      ard[mi][kk] = (const char*)As + (size_t)row * 128 + ((c ^ xv) << 4);
    }
#pragma unroll
  for (int ni = 0; ni < 4; ++ni)
#pragma unroll
    for (int kk = 0; kk < 2; ++kk) {
      int row = wc * 64 + ni * 16 + fr;
      int c = kk * 4 + klane;
      brd[ni][kk] = (const char*)Bs + (size_t)row * 128 + ((c ^ xv) << 4);
    }

  // ---- prologue: stage tiles 0 and 1; retire tile 0; publish.
  STAGE_A(0, 0, 0); STAGE_A(0, 0, 1);
  STAGE_B(0, 0, 0); STAGE_B(0, 0, 1); STAGE_B(0, 0, 2); STAGE_B(0, 0, 3);
  STAGE_A(1, 128, 0); STAGE_A(1, 128, 1);
  STAGE_B(1, 128, 0); STAGE_B(1, 128, 1); STAGE_B(1, 128, 2); STAGE_B(1, 128, 3);
  asm volatile("s_waitcnt vmcnt(6)");      // tile 0 complete, tile 1 in flight
  __builtin_amdgcn_s_barrier();

  // One K-tile, R4 semantics; CUR/NXT are compile-time buffer slots.
#define TILE(t_, CUR, NXT)                                                      \
  do {                                                                          \
    const bool pf = (t_) + 2 < NT;                                              \
    bf16x8 af[4][2], bf[4][2];                                                  \
    _Pragma("unroll") for (int mi = 0; mi < 4; ++mi)                            \
      _Pragma("unroll") for (int kk = 0; kk < 2; ++kk)                          \
        af[mi][kk] = *(const bf16x8*)(ard[mi][kk] + (CUR) * 16384);             \
    _Pragma("unroll") for (int ni = 0; ni < 4; ++ni)                            \
      _Pragma("unroll") for (int kk = 0; kk < 2; ++kk)                          \
        bf[ni][kk] = *(const bf16x8*)(brd[ni][kk] + (CUR) * 32768);             \
    if (pf) {                                                                   \
      const size_t ko_ = (size_t)((t_) + 2) * 128;                              \
      STAGE_A(NXT, ko_, 0); STAGE_A(NXT, ko_, 1);                               \
      STAGE_B(NXT, ko_, 0); STAGE_B(NXT, ko_, 1);                               \
      STAGE_B(NXT, ko_, 2); STAGE_B(NXT, ko_, 3);                               \
    }                                                                           \
    __builtin_amdgcn_s_setprio(1);                                              \
    _Pragma("unroll") for (int mi = 0; mi < 4; ++mi)                            \
      _Pragma("unroll") for (int ni = 0; ni < 4; ++ni)                          \
        _Pragma("unroll") for (int kk = 0; kk < 2; ++kk)                        \
          acc[mi][ni] = __builtin_amdgcn_mfma_f32_16x16x32_bf16(                \
              af[mi][kk], bf[ni][kk], acc[mi][ni], 0, 0, 0);                    \
    __builtin_amdgcn_s_setprio(0);                                              \
    if ((t_) < NT - 1) {                                                        \
      __builtin_amdgcn_sched_barrier(0);                                        \
      if (pf) asm volatile("s_waitcnt vmcnt(6)");                               \
      else    asm volatile("s_waitcnt vmcnt(0)");                               \
    }                                                                           \
    __builtin_amdgcn_s_barrier();                                               \
  } while (0)

  // 63 tiles in 21 x (3-tile unroll with static buffers), then tail tile 63.
#pragma unroll 1
  for (int i = 0; i < 21; ++i) {
    const int t = i * 3;
    TILE(t,     0, 2);
    TILE(t + 1, 1, 0);
    TILE(t + 2, 2, 1);
  }
  TILE(63, 0, 2);   // 63 % 3 == 0; pf=false, no boundary wait

  // ---- epilogue: C/D map: col = lane&15, row = (lane>>4)*4 + reg
  const int cn = lane & 15;
  const int rb = (lane >> 4) * 4;
#pragma unroll
  for (int ai = 0; ai < 4; ++ai)
#pragma unroll
    for (int bj = 0; bj < 4; ++bj) {
      int m0 = bm + wr * 64 + ai * 16 + rb;
      int n0 = bn + wc * 64 + bj * 16 + cn;
#pragma unroll
      for (int r = 0; r < 4; ++r)
        C[(size_t)(m0 + r) * N + n0] = acc[ai][bj][r];
    }
}

extern "C" void kernel_launch(void* const* d_in, const int* in_sizes, int n_in,
                              void* d_out, int out_size, void* d_ws, size_t ws_size,
                              hipStream_t stream) {
  const float* x   = (const float*)d_in[0];
  const float* wsc = (const float*)d_in[1];
  const int*   wq  = (const int*)d_in[2];
  float* out = (float*)d_out;

  const int K = 4096;                 // in_features
  const int N = in_sizes[2] / K;      // out_features = 4096
  const int M = in_sizes[0] / K;      // batch*seq = 2048

  // workspace layout: W bf16 [N*K] then X bf16 [M*K]
  short* Wb = (short*)d_ws;
  short* Xb = Wb + (size_t)N * K;

  int nblkW = (N * K) / 16;           // 1048576
  int n8    = (M * K) / 8;            // 1048576
  int gridP = (nblkW >> 8) + ((n8 + 255) >> 8);
  w4a16_prep<<<gridP, 256, 0, stream>>>(wq, wsc, Wb, nblkW, x, Xb, n8);

  dim3 grid(N / BN, M / BM);
  w4a16_gemm_u3<<<grid, 512, 0, stream>>>(Xb, Wb, out, M, N, K);
}

// Round 17
// 91.996 us; speedup vs baseline: 1.0254x; 1.0254x over previous
//
#include <hip/hip_runtime.h>

typedef __bf16  bf16x8 __attribute__((ext_vector_type(8)));
typedef float   f32x4  __attribute__((ext_vector_type(4)));
typedef short   short8 __attribute__((ext_vector_type(8)));

static __device__ __forceinline__ unsigned short f2bf(float f) {
  union { float f; unsigned int u; } v; v.f = f;
  unsigned int u = v.u;
  u += 0x7fffu + ((u >> 16) & 1u);   // round-to-nearest-even
  return (unsigned short)(u >> 16);
}

// e2m1 decode: code = sign<<3 | e<<1 | m ; values {0,.5,1,1.5,2,3,4,6} * sign
static __device__ __forceinline__ float fp4_decode(int qc) {
  int e = (qc >> 1) & 3;
  float m = (float)(qc & 1);
  float mag = (e == 0) ? (0.5f * m)
                       : ((2.0f + m) * 0.5f * (float)(1 << (e - 1)));
  return (qc & 8) ? -mag : mag;
}

// Fused prep (R4-proven): blocks [0, nblkW/256) dequant W; rest convert x.
__global__ __launch_bounds__(256) void w4a16_prep(
    const int* __restrict__ wq, const float* __restrict__ wsc,
    short* __restrict__ wout, int nblkW,
    const float* __restrict__ x, short* __restrict__ xb, int n8) {
  const int nbW = nblkW >> 8;
  if ((int)blockIdx.x < nbW) {
    int idx = blockIdx.x * 256 + threadIdx.x;
    if (idx >= nblkW) return;
    float s = wsc[idx];
    const int4* qp = (const int4*)wq + (size_t)idx * 4;
    int4 q0 = qp[0], q1 = qp[1], q2 = qp[2], q3 = qp[3];
    short8 r0, r1;
    r0[0] = (short)f2bf(fp4_decode(q0.x) * s);
    r0[1] = (short)f2bf(fp4_decode(q0.y) * s);
    r0[2] = (short)f2bf(fp4_decode(q0.z) * s);
    r0[3] = (short)f2bf(fp4_decode(q0.w) * s);
    r0[4] = (short)f2bf(fp4_decode(q1.x) * s);
    r0[5] = (short)f2bf(fp4_decode(q1.y) * s);
    r0[6] = (short)f2bf(fp4_decode(q1.z) * s);
    r0[7] = (short)f2bf(fp4_decode(q1.w) * s);
    r1[0] = (short)f2bf(fp4_decode(q2.x) * s);
    r1[1] = (short)f2bf(fp4_decode(q2.y) * s);
    r1[2] = (short)f2bf(fp4_decode(q2.z) * s);
    r1[3] = (short)f2bf(fp4_decode(q2.w) * s);
    r1[4] = (short)f2bf(fp4_decode(q3.x) * s);
    r1[5] = (short)f2bf(fp4_decode(q3.y) * s);
    r1[6] = (short)f2bf(fp4_decode(q3.z) * s);
    r1[7] = (short)f2bf(fp4_decode(q3.w) * s);
    short8* op = (short8*)wout + (size_t)idx * 2;
    op[0] = r0;
    op[1] = r1;
  } else {
    int idx = (blockIdx.x - nbW) * 256 + threadIdx.x;
    if (idx >= n8) return;
    const float4* xp = (const float4*)x + (size_t)idx * 2;
    float4 a = xp[0], b = xp[1];
    short8 r;
    r[0] = (short)f2bf(a.x); r[1] = (short)f2bf(a.y);
    r[2] = (short)f2bf(a.z); r[3] = (short)f2bf(a.w);
    r[4] = (short)f2bf(b.x); r[5] = (short)f2bf(b.y);
    r[6] = (short)f2bf(b.z); r[7] = (short)f2bf(b.w);
    ((short8*)xb)[idx] = r;
  }
}

// ---------------------------------------------------------------------------
// C[M,N] = A[M,K] * B[N,K]^T, bf16 in, fp32 out.
// R4's HW-PROVEN skeleton (BM=128 x BN=256, BK=64, 8 waves 2x4, NBUF=3,
// stage-2-ahead, ONE {sched_barrier + vmcnt(6) + s_barrier} per K-tile)
// + R16's VALU win (hoisted ds_read pointers, x3 static-buffer unroll),
// MINUS R16's XCD swizzle (it blew the per-XCD L2 working set: natural
// mapping gives each XCD a bn-slice -> B panel L2-resident, FETCH 82MB;
// the swizzle gave each XCD ALL bn -> 32MB B/XCD thrash, FETCH 139MB).
// Swizzle (T2): 16B-chunk c XOR (row&7) on SOURCE and READ.
// ---------------------------------------------------------------------------
#define BM 128
#define BN 256
#define BK 64
#define NBUF 3
#define ASZ (BM * BK)          // 8192 shorts = 16KB
#define BSZ (BN * BK)          // 16384 shorts = 32KB
#define NT  64                 // K / BK

__global__ __launch_bounds__(512, 2) void w4a16_gemm_u3n(
    const short* __restrict__ A, const short* __restrict__ B,
    float* __restrict__ C, int M, int N, int K) {
  __shared__ __attribute__((aligned(16))) short As[NBUF * ASZ];  // 48KB
  __shared__ __attribute__((aligned(16))) short Bs[NBUF * BSZ];  // 96KB

  const int tid  = threadIdx.x;
  const int lane = tid & 63;
  const int wid  = tid >> 6;      // 0..7
  const int wr   = wid >> 2;      // 0..1  (M)
  const int wc   = wid & 3;       // 0..3  (N)

  // natural mapping (R4-measured FETCH 82MB)
  const int bm = blockIdx.y * BM;
  const int bn = blockIdx.x * BN;

  f32x4 acc[4][4] = {};           // [m-frag][n-frag]

  const int fr    = lane & 15;
  const int klane = lane >> 4;
  const int xv    = fr & 7;       // read-side swizzle XOR

  const size_t rowbytes = (size_t)K * 2;

  // ---- loop-invariant staging addresses (per-thread): only kt varies.
  size_t aoff[2];  int aldso[2];
#pragma unroll
  for (int r = 0; r < 2; ++r) {
    int u = r * 512 + tid;               // 0..1023
    int row = u >> 3, c = u & 7;
    int csrc = c ^ (row & 7);
    aoff[r]  = (size_t)(bm + row) * rowbytes + (size_t)csrc * 16;
    aldso[r] = u * 16;
  }
  size_t boff[4];  int bldso[4];
#pragma unroll
  for (int r = 0; r < 4; ++r) {
    int u = r * 512 + tid;               // 0..2047
    int row = u >> 3, c = u & 7;
    int csrc = c ^ (row & 7);
    boff[r]  = (size_t)(bn + row) * rowbytes + (size_t)csrc * 16;
    bldso[r] = u * 16;
  }

  const char* Ag = (const char*)A;
  const char* Bg = (const char*)B;

#define STAGE_A(bufn, koff2, r)                                                 \
  __builtin_amdgcn_global_load_lds(                                             \
      (const __attribute__((address_space(1))) unsigned int*)(Ag + aoff[r] + (koff2)), \
      (__attribute__((address_space(3))) unsigned int*)((char*)As + (bufn) * 16384 + aldso[r]), \
      16, 0, 0)
#define STAGE_B(bufn, koff2, r)                                                 \
  __builtin_amdgcn_global_load_lds(                                             \
      (const __attribute__((address_space(1))) unsigned int*)(Bg + boff[r] + (koff2)), \
      (__attribute__((address_space(3))) unsigned int*)((char*)Bs + (bufn) * 32768 + bldso[r]), \
      16, 0, 0)

  // ---- loop-invariant fragment-read pointers (buf 0 base; buf offset is a
  //      compile-time immediate in the unrolled loop)
  const char* ard[4][2];
  const char* brd[4][2];
#pragma unroll
  for (int mi = 0; mi < 4; ++mi)
#pragma unroll
    for (int kk = 0; kk < 2; ++kk) {
      int row = wr * 64 + mi * 16 + fr;
      int c = kk * 4 + klane;
      ard[mi][kk] = (const char*)As + (size_t)row * 128 + ((c ^ xv) << 4);
    }
#pragma unroll
  for (int ni = 0; ni < 4; ++ni)
#pragma unroll
    for (int kk = 0; kk < 2; ++kk) {
      int row = wc * 64 + ni * 16 + fr;
      int c = kk * 4 + klane;
      brd[ni][kk] = (const char*)Bs + (size_t)row * 128 + ((c ^ xv) << 4);
    }

  // ---- prologue: stage tiles 0 and 1; retire tile 0; publish.
  STAGE_A(0, 0, 0); STAGE_A(0, 0, 1);
  STAGE_B(0, 0, 0); STAGE_B(0, 0, 1); STAGE_B(0, 0, 2); STAGE_B(0, 0, 3);
  STAGE_A(1, 128, 0); STAGE_A(1, 128, 1);
  STAGE_B(1, 128, 0); STAGE_B(1, 128, 1); STAGE_B(1, 128, 2); STAGE_B(1, 128, 3);
  asm volatile("s_waitcnt vmcnt(6)");      // tile 0 complete, tile 1 in flight
  __builtin_amdgcn_s_barrier();

  // One K-tile, R4 semantics; CUR/NXT are compile-time buffer slots.
#define TILE(t_, CUR, NXT)                                                      \
  do {                                                                          \
    const bool pf = (t_) + 2 < NT;                                              \
    bf16x8 af[4][2], bf[4][2];                                                  \
    _Pragma("unroll") for (int mi = 0; mi < 4; ++mi)                            \
      _Pragma("unroll") for (int kk = 0; kk < 2; ++kk)                          \
        af[mi][kk] = *(const bf16x8*)(ard[mi][kk] + (CUR) * 16384);             \
    _Pragma("unroll") for (int ni = 0; ni < 4; ++ni)                            \
      _Pragma("unroll") for (int kk = 0; kk < 2; ++kk)                          \
        bf[ni][kk] = *(const bf16x8*)(brd[ni][kk] + (CUR) * 32768);             \
    if (pf) {                                                                   \
      const size_t ko_ = (size_t)((t_) + 2) * 128;                              \
      STAGE_A(NXT, ko_, 0); STAGE_A(NXT, ko_, 1);                               \
      STAGE_B(NXT, ko_, 0); STAGE_B(NXT, ko_, 1);                               \
      STAGE_B(NXT, ko_, 2); STAGE_B(NXT, ko_, 3);                               \
    }                                                                           \
    __builtin_amdgcn_s_setprio(1);                                              \
    _Pragma("unroll") for (int mi = 0; mi < 4; ++mi)                            \
      _Pragma("unroll") for (int ni = 0; ni < 4; ++ni)                          \
        _Pragma("unroll") for (int kk = 0; kk < 2; ++kk)                        \
          acc[mi][ni] = __builtin_amdgcn_mfma_f32_16x16x32_bf16(                \
              af[mi][kk], bf[ni][kk], acc[mi][ni], 0, 0, 0);                    \
    __builtin_amdgcn_s_setprio(0);                                              \
    if ((t_) < NT - 1) {                                                        \
      __builtin_amdgcn_sched_barrier(0);                                        \
      if (pf) asm volatile("s_waitcnt vmcnt(6)");                               \
      else    asm volatile("s_waitcnt vmcnt(0)");                               \
    }                                                                           \
    __builtin_amdgcn_s_barrier();                                               \
  } while (0)

  // 63 tiles in 21 x (3-tile unroll with static buffers), then tail tile 63.
#pragma unroll 1
  for (int i = 0; i < 21; ++i) {
    const int t = i * 3;
    TILE(t,     0, 2);
    TILE(t + 1, 1, 0);
    TILE(t + 2, 2, 1);
  }
  TILE(63, 0, 2);   // 63 % 3 == 0; pf=false, no boundary wait

  // ---- epilogue: C/D map: col = lane&15, row = (lane>>4)*4 + reg
  const int cn = lane & 15;
  const int rb = (lane >> 4) * 4;
#pragma unroll
  for (int ai = 0; ai < 4; ++ai)
#pragma unroll
    for (int bj = 0; bj < 4; ++bj) {
      int m0 = bm + wr * 64 + ai * 16 + rb;
      int n0 = bn + wc * 64 + bj * 16 + cn;
#pragma unroll
      for (int r = 0; r < 4; ++r)
        C[(size_t)(m0 + r) * N + n0] = acc[ai][bj][r];
    }
}

extern "C" void kernel_launch(void* const* d_in, const int* in_sizes, int n_in,
                              void* d_out, int out_size, void* d_ws, size_t ws_size,
                              hipStream_t stream) {
  const float* x   = (const float*)d_in[0];
  const float* wsc = (const float*)d_in[1];
  const int*   wq  = (const int*)d_in[2];
  float* out = (float*)d_out;

  const int K = 4096;                 // in_features
  const int N = in_sizes[2] / K;      // out_features = 4096
  const int M = in_sizes[0] / K;      // batch*seq = 2048

  // workspace layout: W bf16 [N*K] then X bf16 [M*K]
  short* Wb = (short*)d_ws;
  short* Xb = Wb + (size_t)N * K;

  int nblkW = (N * K) / 16;           // 1048576
  int n8    = (M * K) / 8;            // 1048576
  int gridP = (nblkW >> 8) + ((n8 + 255) >> 8);
  w4a16_prep<<<gridP, 256, 0, stream>>>(wq, wsc, Wb, nblkW, x, Xb, n8);

  dim3 grid(N / BN, M / BM);
  w4a16_gemm_u3n<<<grid, 512, 0, stream>>>(Xb, Wb, out, M, N, K);
}

// Round 18
// 90.756 us; speedup vs baseline: 1.0394x; 1.0137x over previous
//
#include <hip/hip_runtime.h>

typedef __bf16  bf16x8 __attribute__((ext_vector_type(8)));
typedef float   f32x4  __attribute__((ext_vector_type(4)));
typedef short   short8 __attribute__((ext_vector_type(8)));

static __device__ __forceinline__ unsigned short f2bf(float f) {
  union { float f; unsigned int u; } v; v.f = f;
  unsigned int u = v.u;
  u += 0x7fffu + ((u >> 16) & 1u);   // round-to-nearest-even
  return (unsigned short)(u >> 16);
}

// e2m1 decode: code = sign<<3 | e<<1 | m ; values {0,.5,1,1.5,2,3,4,6} * sign
static __device__ __forceinline__ float fp4_decode(int qc) {
  int e = (qc >> 1) & 3;
  float m = (float)(qc & 1);
  float mag = (e == 0) ? (0.5f * m)
                       : ((2.0f + m) * 0.5f * (float)(1 << (e - 1)));
  return (qc & 8) ? -mag : mag;
}

// Fused prep: blocks [0, nblkW/256) dequant W; rest convert x.
// Prep is HBM-read-bound at its floor: 117MB compulsory reads ~= 18.6us.
__global__ __launch_bounds__(256) void w4a16_prep(
    const int* __restrict__ wq, const float* __restrict__ wsc,
    short* __restrict__ wout, int nblkW,
    const float* __restrict__ x, short* __restrict__ xb, int n8) {
  const int nbW = nblkW >> 8;
  if ((int)blockIdx.x < nbW) {
    int idx = blockIdx.x * 256 + threadIdx.x;
    if (idx >= nblkW) return;
    float s = wsc[idx];
    const int4* qp = (const int4*)wq + (size_t)idx * 4;
    int4 q0 = qp[0], q1 = qp[1], q2 = qp[2], q3 = qp[3];
    short8 r0, r1;
    r0[0] = (short)f2bf(fp4_decode(q0.x) * s);
    r0[1] = (short)f2bf(fp4_decode(q0.y) * s);
    r0[2] = (short)f2bf(fp4_decode(q0.z) * s);
    r0[3] = (short)f2bf(fp4_decode(q0.w) * s);
    r0[4] = (short)f2bf(fp4_decode(q1.x) * s);
    r0[5] = (short)f2bf(fp4_decode(q1.y) * s);
    r0[6] = (short)f2bf(fp4_decode(q1.z) * s);
    r0[7] = (short)f2bf(fp4_decode(q1.w) * s);
    r1[0] = (short)f2bf(fp4_decode(q2.x) * s);
    r1[1] = (short)f2bf(fp4_decode(q2.y) * s);
    r1[2] = (short)f2bf(fp4_decode(q2.z) * s);
    r1[3] = (short)f2bf(fp4_decode(q2.w) * s);
    r1[4] = (short)f2bf(fp4_decode(q3.x) * s);
    r1[5] = (short)f2bf(fp4_decode(q3.y) * s);
    r1[6] = (short)f2bf(fp4_decode(q3.z) * s);
    r1[7] = (short)f2bf(fp4_decode(q3.w) * s);
    short8* op = (short8*)wout + (size_t)idx * 2;
    op[0] = r0;
    op[1] = r1;
  } else {
    int idx = (blockIdx.x - nbW) * 256 + threadIdx.x;
    if (idx >= n8) return;
    const float4* xp = (const float4*)x + (size_t)idx * 2;
    float4 a = xp[0], b = xp[1];
    short8 r;
    r[0] = (short)f2bf(a.x); r[1] = (short)f2bf(a.y);
    r[2] = (short)f2bf(a.z); r[3] = (short)f2bf(a.w);
    r[4] = (short)f2bf(b.x); r[5] = (short)f2bf(b.y);
    r[6] = (short)f2bf(b.z); r[7] = (short)f2bf(b.w);
    ((short8*)xb)[idx] = r;
  }
}

// ---------------------------------------------------------------------------
// C[M,N] = A[M,K] * B[N,K]^T, bf16 in, fp32 out.  [R4 — empirical best]
// BM=128 x BN=256, BK=64, 8 waves (2x4), per-wave 64x64.
// ONE phase / ONE raw barrier per K-tile: {16 ds_read + 6 stage-issue ->
// 32 MFMA (compiler-counted lgkm) -> sched_barrier -> vmcnt(6) -> s_barrier}.
// Triple-buffered LDS (144KB); counted vmcnt never drains in steady state.
// LDS swizzle (T2): 16B-chunk c XOR (row&7) on stage-SOURCE and on READ.
// Measured (R4): 69.0us GEMM = 996 TF, MfmaUtil 42%, conflicts 0, FETCH 82MB.
// Probed-and-null levers: schedule variants (R3/R11/R12/R13), multi-block
// occupancy (R1/R6), A-from-global (R5/R10), K-split reads -25% (R15),
// addr-VALU hoist (R17), XCD swizzle (R16: hurts L2 working set).
// Residual ~1100 cyc/tile = latency/barrier floor of this wave geometry;
// the 256^2 8-phase escape needs >=256-block grids (M=2048 gives 128).
// ---------------------------------------------------------------------------
#define BM 128
#define BN 256
#define BK 64
#define NBUF 3
#define ASZ (BM * BK)          // 8192 shorts = 16KB
#define BSZ (BN * BK)          // 16384 shorts = 32KB

__global__ __launch_bounds__(512, 2) void w4a16_gemm_1ph(
    const short* __restrict__ A, const short* __restrict__ B,
    float* __restrict__ C, int M, int N, int K) {
  __shared__ __attribute__((aligned(16))) short As[NBUF * ASZ];  // 48KB
  __shared__ __attribute__((aligned(16))) short Bs[NBUF * BSZ];  // 96KB

  const int tid  = threadIdx.x;
  const int lane = tid & 63;
  const int wid  = tid >> 6;      // 0..7
  const int wr   = wid >> 2;      // 0..1  (M)
  const int wc   = wid & 3;       // 0..3  (N)

  const int bm = blockIdx.y * BM;
  const int bn = blockIdx.x * BN;

  f32x4 acc[4][4] = {};           // [m-frag][n-frag]

  const int fr    = lane & 15;
  const int klane = lane >> 4;
  const int xv    = fr & 7;       // read-side swizzle XOR

  const size_t rowbytes = (size_t)K * 2;

  // ---- loop-invariant staging addresses (per-thread): only kt varies.
  size_t aoff[2];  int aldso[2];
#pragma unroll
  for (int r = 0; r < 2; ++r) {
    int u = r * 512 + tid;               // 0..1023
    int row = u >> 3, c = u & 7;
    int csrc = c ^ (row & 7);
    aoff[r]  = (size_t)(bm + row) * rowbytes + (size_t)csrc * 16;
    aldso[r] = u * 16;
  }
  size_t boff[4];  int bldso[4];
#pragma unroll
  for (int r = 0; r < 4; ++r) {
    int u = r * 512 + tid;               // 0..2047
    int row = u >> 3, c = u & 7;
    int csrc = c ^ (row & 7);
    boff[r]  = (size_t)(bn + row) * rowbytes + (size_t)csrc * 16;
    bldso[r] = u * 16;
  }

  const char* Ag = (const char*)A;
  const char* Bg = (const char*)B;

#define STAGE_A(bufbase, koff2, r)                                              \
  __builtin_amdgcn_global_load_lds(                                             \
      (const __attribute__((address_space(1))) unsigned int*)(Ag + aoff[r] + (koff2)), \
      (__attribute__((address_space(3))) unsigned int*)((char*)(bufbase) + aldso[r]),  \
      16, 0, 0)
#define STAGE_B(bufbase, koff2, r)                                              \
  __builtin_amdgcn_global_load_lds(                                             \
      (const __attribute__((address_space(1))) unsigned int*)(Bg + boff[r] + (koff2)), \
      (__attribute__((address_space(3))) unsigned int*)((char*)(bufbase) + bldso[r]),  \
      16, 0, 0)

  // swizzled fragment reads
  auto readA = [&](const short* Ab, int mi, int kk) -> bf16x8 {
    int row = wr * 64 + mi * 16 + fr;
    int c = kk * 4 + klane;
    return *(const bf16x8*)((const char*)Ab + (size_t)row * 128 + ((c ^ xv) << 4));
  };
  auto readB = [&](const short* Bb, int ni, int kk) -> bf16x8 {
    int row = wc * 64 + ni * 16 + fr;
    int c = kk * 4 + klane;
    return *(const bf16x8*)((const char*)Bb + (size_t)row * 128 + ((c ^ xv) << 4));
  };

  const int NT = K / BK;   // 64

  // ---- prologue: stage tiles 0 and 1; confirm tile 0 resident.
  {
    char* A0 = (char*)As; char* B0 = (char*)Bs;
    char* A1 = (char*)(As + ASZ); char* B1 = (char*)(Bs + BSZ);
    STAGE_A(A0, 0, 0); STAGE_A(A0, 0, 1);
    STAGE_B(B0, 0, 0); STAGE_B(B0, 0, 1); STAGE_B(B0, 0, 2); STAGE_B(B0, 0, 3);
    size_t k2 = (size_t)BK * 2;
    STAGE_A(A1, k2, 0); STAGE_A(A1, k2, 1);
    STAGE_B(B1, k2, 0); STAGE_B(B1, k2, 1); STAGE_B(B1, k2, 2); STAGE_B(B1, k2, 3);
  }
  asm volatile("s_waitcnt vmcnt(6)");      // tile 0 complete, tile 1 in flight
  __builtin_amdgcn_s_barrier();

  int cur = 0, nxt = 2;
  for (int t = 0; t < NT; ++t) {
    const short* Ab = As + cur * ASZ;
    const short* Bb = Bs + cur * BSZ;
    char* An = (char*)(As + nxt * ASZ);
    char* Bn = (char*)(Bs + nxt * BSZ);
    const size_t koff2 = (size_t)(t + 2) * (BK * 2);
    const bool pf = (t + 2) < NT;

    bf16x8 af0[2][2], bfr[4][2], af1[2][2];

    // issue all fragment reads for tile t (A-mq0, B, A-mq1 order)
#pragma unroll
    for (int mi = 0; mi < 2; ++mi)
#pragma unroll
      for (int kk = 0; kk < 2; ++kk)
        af0[mi][kk] = readA(Ab, 0 * 2 + mi, kk);
#pragma unroll
    for (int ni = 0; ni < 4; ++ni)
#pragma unroll
      for (int kk = 0; kk < 2; ++kk)
        bfr[ni][kk] = readB(Bb, ni, kk);
#pragma unroll
    for (int mi = 0; mi < 2; ++mi)
#pragma unroll
      for (int kk = 0; kk < 2; ++kk)
        af1[mi][kk] = readA(Ab, 1 * 2 + mi, kk);

    // issue all 6 stage loads for tile t+2
    if (pf) {
      STAGE_A(An, koff2, 0); STAGE_A(An, koff2, 1);
      STAGE_B(Bn, koff2, 0); STAGE_B(Bn, koff2, 1);
      STAGE_B(Bn, koff2, 2); STAGE_B(Bn, koff2, 3);
    }

    // 32 MFMA; compiler inserts counted lgkmcnt before first uses
    __builtin_amdgcn_s_setprio(1);
#pragma unroll
    for (int mi = 0; mi < 2; ++mi)
#pragma unroll
      for (int ni = 0; ni < 4; ++ni)
#pragma unroll
        for (int kk = 0; kk < 2; ++kk)
          acc[mi][ni] = __builtin_amdgcn_mfma_f32_16x16x32_bf16(
              af0[mi][kk], bfr[ni][kk], acc[mi][ni], 0, 0, 0);
#pragma unroll
    for (int mi = 0; mi < 2; ++mi)
#pragma unroll
      for (int ni = 0; ni < 4; ++ni)
#pragma unroll
        for (int kk = 0; kk < 2; ++kk)
          acc[2 + mi][ni] = __builtin_amdgcn_mfma_f32_16x16x32_bf16(
              af1[mi][kk], bfr[ni][kk], acc[2 + mi][ni], 0, 0, 0);
    __builtin_amdgcn_s_setprio(0);

    // boundary: pin issue order, confirm tile t+1 resident (my writes), publish
    if (t < NT - 1) {
      __builtin_amdgcn_sched_barrier(0);
      if (pf) asm volatile("s_waitcnt vmcnt(6)");
      else    asm volatile("s_waitcnt vmcnt(0)");
    }
    __builtin_amdgcn_s_barrier();

    cur = (cur == NBUF - 1) ? 0 : cur + 1;
    nxt = (nxt == NBUF - 1) ? 0 : nxt + 1;
  }

  // ---- epilogue: C/D map: col = lane&15, row = (lane>>4)*4 + reg
  const int cn = lane & 15;
  const int rb = (lane >> 4) * 4;
#pragma unroll
  for (int ai = 0; ai < 4; ++ai)
#pragma unroll
    for (int bj = 0; bj < 4; ++bj) {
      int m0 = bm + wr * 64 + ai * 16 + rb;
      int n0 = bn + wc * 64 + bj * 16 + cn;
#pragma unroll
      for (int r = 0; r < 4; ++r)
        C[(size_t)(m0 + r) * N + n0] = acc[ai][bj][r];
    }
}

extern "C" void kernel_launch(void* const* d_in, const int* in_sizes, int n_in,
                              void* d_out, int out_size, void* d_ws, size_t ws_size,
                              hipStream_t stream) {
  const float* x   = (const float*)d_in[0];
  const float* wsc = (const float*)d_in[1];
  const int*   wq  = (const int*)d_in[2];
  float* out = (float*)d_out;

  const int K = 4096;                 // in_features
  const int N = in_sizes[2] / K;      // out_features = 4096
  const int M = in_sizes[0] / K;      // batch*seq = 2048

  // workspace layout: W bf16 [N*K] then X bf16 [M*K]
  short* Wb = (short*)d_ws;
  short* Xb = Wb + (size_t)N * K;

  int nblkW = (N * K) / 16;           // 1048576
  int n8    = (M * K) / 8;            // 1048576
  int gridP = (nblkW >> 8) + ((n8 + 255) >> 8);
  w4a16_prep<<<gridP, 256, 0, stream>>>(wq, wsc, Wb, nblkW, x, Xb, n8);

  dim3 grid(N / BN, M / BM);
  w4a16_gemm_1ph<<<grid, 512, 0, stream>>>(Xb, Wb, out, M, N, K);
}